// Round 5
// baseline (271.779 us; speedup 1.0000x reference)
//
#include <hip/hip_runtime.h>
#include <hip/hip_bf16.h>
#include <math.h>

#define N_TOK 32768
#define C_DIM 256
#define F_DIM 1024
#define E_NUM 16
#define TILE_R 128
#define NCH 16

typedef unsigned short u16;
typedef unsigned int u32;
typedef __attribute__((ext_vector_type(4))) u16 u16x4;
typedef __attribute__((ext_vector_type(8))) u16 u16x8;
typedef __attribute__((ext_vector_type(8))) short bf16x8;
typedef __attribute__((ext_vector_type(4))) u32 u32x4;
typedef __attribute__((ext_vector_type(4))) float f32x4;
typedef __attribute__((ext_vector_type(16))) float f32x16;

#define AS1 __attribute__((address_space(1)))
#define AS3 __attribute__((address_space(3)))

// async global->LDS: HW writes wave-uniform LDS base + lane*16
__device__ __forceinline__ void gload16(const void* g, void* lds) {
    __builtin_amdgcn_global_load_lds((const AS1 u32*)(uintptr_t)g,
                                     (AS3 u32*)(u32)(uintptr_t)lds, 16, 0, 0);
}

__device__ __forceinline__ u16 f2bf(float f) {
    union { float f; u32 u; } v; v.f = f;
    u32 r = v.u + 0x7fffu + ((v.u >> 16) & 1u);   // RNE
    return (u16)(r >> 16);
}

// ---------------- workspace layout (bytes) ----------------
// 0        topk_idx int[2N]
// 262144   topk_w   f32[2N]
// 524288   tok      int[2N]
// 786432   wgt      f32[2N]
// 1048576  pairpos  int[2N]
// 1310720  counts[16] fill[16] offs[17] tp[17]
// 2097152  xb   bf16[N][C]
// 18874368 w1t  bf16[E][F][C]
// 27262976 w2t  bf16[E][C][F]
// 35651584 ybuf f32[2N][C]  (MODE 0 only)

// ---- gate: 64 tokens/block, 4 lanes/token, fused x->bf16 conversion ----
__global__ __launch_bounds__(256) void gate_kernel(
    const float* __restrict__ x, const float* __restrict__ gW,
    const float* __restrict__ gb, float* __restrict__ ent_out,
    int* __restrict__ tidx, float* __restrict__ tw, int* __restrict__ counts,
    u16* __restrict__ xb)
{
    __shared__ float gws[E_NUM * C_DIM];
    __shared__ float gbs[E_NUM];
    __shared__ float went[4];
    __shared__ int lc[E_NUM];
    int tid = threadIdx.x;

    for (int i = tid; i < E_NUM * C_DIM / 4; i += 256)
        ((float4*)gws)[i] = ((const float4*)gW)[i];
    if (tid < E_NUM) { gbs[tid] = gb[tid]; lc[tid] = 0; }
    __syncthreads();

    int tok = tid >> 2, q = tid & 3;
    int n = blockIdx.x * 64 + tok;
    const float* xr = x + (size_t)n * C_DIM;

    float4 xv[16];
    #pragma unroll
    for (int j = 0; j < 16; j++)
        xv[j] = *(const float4*)(xr + j * 16 + q * 4);

    #pragma unroll
    for (int j = 0; j < 16; j++) {
        u16x4 o;
        o[0] = f2bf(xv[j].x); o[1] = f2bf(xv[j].y);
        o[2] = f2bf(xv[j].z); o[3] = f2bf(xv[j].w);
        *(u16x4*)(xb + (size_t)n * C_DIM + j * 16 + q * 4) = o;
    }

    float lg[E_NUM];
    #pragma unroll
    for (int e = 0; e < E_NUM; e++) lg[e] = 0.f;
    #pragma unroll
    for (int j = 0; j < 16; j++) {
        #pragma unroll
        for (int e = 0; e < E_NUM; e++) {
            float4 g = *(const float4*)(gws + e * C_DIM + j * 16 + q * 4);
            lg[e] += xv[j].x * g.x + xv[j].y * g.y + xv[j].z * g.z + xv[j].w * g.w;
        }
    }
    #pragma unroll
    for (int e = 0; e < E_NUM; e++) {
        lg[e] += __shfl_xor(lg[e], 1);
        lg[e] += __shfl_xor(lg[e], 2);
        lg[e] += gbs[e];
    }

    float m = lg[0];
    #pragma unroll
    for (int e = 1; e < E_NUM; e++) m = fmaxf(m, lg[e]);
    float s = 0.f, ex[E_NUM];
    #pragma unroll
    for (int e = 0; e < E_NUM; e++) { ex[e] = __expf(lg[e] - m); s += ex[e]; }
    float inv = 1.f / s;
    float ent = 0.f;
    #pragma unroll
    for (int e = 0; e < E_NUM; e++) {
        float p = ex[e] * inv;
        ent -= p * logf(p + 1e-8f);
    }

    float v0 = -1e30f, v1 = -1e30f;
    int i0 = 0, i1 = 0;
    #pragma unroll
    for (int e = 0; e < E_NUM; e++) {
        float l = lg[e];
        if (l > v0) { v1 = v0; i1 = i0; v0 = l; i0 = e; }
        else if (l > v1) { v1 = l; i1 = e; }
    }
    if (q == 0) {
        float w1e = __expf(v1 - v0);
        float z = 1.f + w1e;
        tidx[2 * n] = i0; tidx[2 * n + 1] = i1;
        tw[2 * n] = 1.f / z; tw[2 * n + 1] = w1e / z;
        atomicAdd(&lc[i0], 1);
        atomicAdd(&lc[i1], 1);
    }

    float v = ent;   // 4x duplicated per token -> scale 1/(4N)
    for (int off = 32; off > 0; off >>= 1) v += __shfl_down(v, off);
    int wid = tid >> 6, lane = tid & 63;
    if (lane == 0) went[wid] = v;
    __syncthreads();
    if (tid == 0)
        atomicAdd(ent_out, (went[0] + went[1] + went[2] + went[3]) * (1.0f / (4.0f * N_TOK)));
    if (tid < E_NUM && lc[tid]) atomicAdd(&counts[tid], lc[tid]);
}

__global__ void prefix_kernel(const int* __restrict__ counts,
                              int* __restrict__ offs, int* __restrict__ tp)
{
    if (threadIdx.x == 0 && blockIdx.x == 0) {
        int o = 0, t = 0;
        offs[0] = 0; tp[0] = 0;
        for (int e = 0; e < E_NUM; e++) {
            o += counts[e];
            t += (counts[e] + TILE_R - 1) / TILE_R;
            offs[e + 1] = o;
            tp[e + 1] = t;
        }
    }
}

__global__ __launch_bounds__(256) void scatter_kernel(
    const int* __restrict__ tidx, const float* __restrict__ tw,
    const int* __restrict__ offs, int* __restrict__ fill,
    int* __restrict__ tok, float* __restrict__ wgt, int* __restrict__ pairpos)
{
    __shared__ int lc[E_NUM], lbase[E_NUM];
    int tid = threadIdx.x;
    if (tid < E_NUM) lc[tid] = 0;
    __syncthreads();
    int n = blockIdx.x * 256 + tid;
    int e0 = tidx[2 * n], e1 = tidx[2 * n + 1];
    int r0 = atomicAdd(&lc[e0], 1);
    int r1 = atomicAdd(&lc[e1], 1);
    __syncthreads();
    if (tid < E_NUM) lbase[tid] = offs[tid] + atomicAdd(&fill[tid], lc[tid]);
    __syncthreads();
    int p0 = lbase[e0] + r0, p1 = lbase[e1] + r1;
    tok[p0] = n; wgt[p0] = tw[2 * n];     pairpos[2 * n] = p0;
    tok[p1] = n; wgt[p1] = tw[2 * n + 1]; pairpos[2 * n + 1] = p1;
}

// per-expert transpose+convert: src f32 [R][Cc] -> dst bf16 [Cc][R]
__global__ __launch_bounds__(256) void tcvt_kernel(
    const float* __restrict__ src, u16* __restrict__ dst, int R, int Cc)
{
    __shared__ float t[64][65];
    int e = blockIdx.x;
    int r0 = blockIdx.y << 6, c0 = blockIdx.z << 6;
    const float* s = src + (size_t)e * R * Cc;
    u16* d = dst + (size_t)e * R * Cc;
    int tid = threadIdx.x;
    int rr = tid >> 4, cc = (tid & 15) << 2;
    #pragma unroll
    for (int it = 0; it < 4; it++) {
        float4 v = *(const float4*)(s + (size_t)(r0 + rr + it * 16) * Cc + c0 + cc);
        t[rr + it * 16][cc] = v.x; t[rr + it * 16][cc + 1] = v.y;
        t[rr + it * 16][cc + 2] = v.z; t[rr + it * 16][cc + 3] = v.w;
    }
    __syncthreads();
    int cr = tid >> 3, rq = (tid & 7) << 3;
    #pragma unroll
    for (int it = 0; it < 2; it++) {
        int c = cr + it * 32;
        u16x8 o;
        #pragma unroll
        for (int j = 0; j < 8; j++) o[j] = f2bf(t[rq + j][c]);
        *(u16x8*)(d + (size_t)(c0 + c) * R + r0 + rq) = o;
    }
}

// ---- FFN: 128-token tile, 8 waves, 32x32x16 MFMA ----
// LDS: w1s dbuf 2x32K @0 | w2s dbuf 2x32K @65536 | b1s 4K @131072 | tok/w
// x fragments live in registers (loaded once via LDS prologue).
#define W2S_OFF 65536
#define B1S_OFF 131072

#define STORE_HALF(B)                                                         \
    _Pragma("unroll")                                                         \
    for (int j = 0; j < 4; j++) {                                             \
        _Pragma("unroll")                                                     \
        for (int rq = 0; rq < 4; rq++) {                                      \
            float4 v = {acc2[(B) + j][4 * rq],     acc2[(B) + j][4 * rq + 1], \
                        acc2[(B) + j][4 * rq + 2], acc2[(B) + j][4 * rq + 3]};\
            *(float4*)(myslot + ((((j << 2) + rq) << 6) + lane) * 4) = v;     \
        }                                                                     \
    }

#define REDUCE_HALF(B)                                                        \
    _Pragma("unroll")                                                         \
    for (int j = 0; j < 4; j++) {                                             \
        _Pragma("unroll")                                                     \
        for (int rq = 0; rq < 4; rq++) {                                      \
            float4 v = *(const float4*)(pslot + ((((j << 2) + rq) << 6) + lane) * 4); \
            acc2[(B) + j][4 * rq]     += v.x;                                 \
            acc2[(B) + j][4 * rq + 1] += v.y;                                 \
            acc2[(B) + j][4 * rq + 2] += v.z;                                 \
            acc2[(B) + j][4 * rq + 3] += v.w;                                 \
        }                                                                     \
    }

#define WRITE_Y(B)                                                            \
    _Pragma("unroll")                                                         \
    for (int j = 0; j < 4; j++) {                                             \
        _Pragma("unroll")                                                     \
        for (int rq = 0; rq < 4; rq++) {                                      \
            int c = (((B) + j) << 5) + (rq << 3) + (hi << 2);                 \
            float4 v = {acc2[(B) + j][4 * rq],     acc2[(B) + j][4 * rq + 1], \
                        acc2[(B) + j][4 * rq + 2], acc2[(B) + j][4 * rq + 3]};\
            *(float4*)(yr + c) = v;                                           \
        }                                                                     \
    }

#define WRITE_ATOMIC(B)                                                       \
    _Pragma("unroll")                                                         \
    for (int j = 0; j < 4; j++) {                                             \
        _Pragma("unroll")                                                     \
        for (int rq = 0; rq < 4; rq++) {                                      \
            int c = (((B) + j) << 5) + (rq << 3) + (hi << 2);                 \
            _Pragma("unroll")                                                 \
            for (int l = 0; l < 4; l++)                                       \
                atomicAdd(&orow[c + l],                                       \
                          wgt_m * (acc2[(B) + j][4 * rq + l] + b2e[c + l]));  \
        }                                                                     \
    }

template <int MODE>
__global__ __launch_bounds__(512, 2) void ffn_mfma(
    const u16* __restrict__ xb, const u16* __restrict__ w1t,
    const u16* __restrict__ w2t, const float* __restrict__ b1,
    const float* __restrict__ b2, const int* __restrict__ tok,
    const float* __restrict__ wgt, const int* __restrict__ offs,
    const int* __restrict__ tp, float* __restrict__ ybuf,
    float* __restrict__ out)
{
    __shared__ __align__(1024) char smem[136192];
    int* s_tok = (int*)(smem + 135168);
    float* s_w = (float*)(smem + 135680);
    float* b1s = (float*)(smem + B1S_OFF);

    int b = blockIdx.x;
    if (b >= tp[E_NUM]) return;
    int e = 0;
    while (b >= tp[e + 1]) e++;
    int base = offs[e] + ((b - tp[e]) << 7);
    int rows = offs[e + 1] - base; if (rows > TILE_R) rows = TILE_R;

    int tid = threadIdx.x;
    int lane = tid & 63, wid = tid >> 6;
    int hi = lane >> 5;
    int wr = wid >> 1, wc = wid & 1;

    const u16* w1e = w1t + (size_t)e * (F_DIM * C_DIM);   // [F][C]
    const u16* w2e = w2t + (size_t)e * (C_DIM * F_DIM);   // [C][F]
    const float* b1e = b1 + e * F_DIM;
    const float* b2e = b2 + e * C_DIM;

    if (tid < TILE_R) {
        int src = (tid < rows) ? base + tid : base;
        s_tok[tid] = tok[src];
        s_w[tid] = (tid < rows) ? wgt[src] : 0.f;
    }
    if (tid < 256) ((float4*)b1s)[tid] = ((const float4*)b1e)[tid];
    __syncthreads();

    // ---- prologue: stage x tile through LDS (w1s region), hoist to regs ----
    #pragma unroll
    for (int i = 0; i < 8; i++) {
        int idx = (wid << 3) + i;
        int row = ((idx >> 4) << 5) + (lane & 31);
        const u16* src = xb + ((size_t)s_tok[row] << 8) + ((idx & 15) << 4) + (hi << 3);
        gload16(src, smem + (idx << 10));
    }
    __syncthreads();   // x staged

    bf16x8 xr[16];     // this wave's m-tile (wr), all 16 k-slices: 64 VGPR
    #pragma unroll
    for (int ks = 0; ks < 16; ks++)
        xr[ks] = *(const bf16x8*)(smem + (wr << 14) + (ks << 10) + (lane << 4));
    __syncthreads();   // xr in regs; w1s region free for dbuf

    // stage chunks 0 and 1 into the two buffers
    #pragma unroll
    for (int cur = 0; cur < 2; cur++) {
        #pragma unroll
        for (int i = 0; i < 4; i++) {
            int idx = (wid << 2) + i;
            int f = (cur << 6) + ((idx >> 4) << 5) + (lane & 31);
            gload16(w1e + ((size_t)f << 8) + ((idx & 15) << 4) + (hi << 3),
                    smem + (cur << 15) + (idx << 10));
        }
        #pragma unroll
        for (int i = 0; i < 4; i++) {
            int idx = (wid << 2) + i;
            int c = ((idx >> 2) << 5) + (lane & 31);
            gload16(w2e + ((size_t)c << 10) + (cur << 6) + ((idx & 3) << 4) + (hi << 3),
                    smem + W2S_OFF + (cur << 15) + (idx << 10));
        }
    }

    f32x16 acc2[8];
    #pragma unroll
    for (int ct = 0; ct < 8; ct++) acc2[ct] = (f32x16)(0.0f);

    for (int ch = 0; ch < NCH; ch++) {
        int cur = ch & 1;
        __syncthreads();   // drains this chunk's loads (1 compute-phase old);
                           // also fences buffer reuse across iterations

        const char* w1b = smem + (cur << 15) + (wc << 14) + (lane << 4);
        const char* w2b = smem + W2S_OFF + (cur << 15) + (lane << 4);

        // ---- phase 1: Ht = W1 x X^T (swapped) -> D[f][m], col=m=lane&31 ----
        f32x16 acc1 = (f32x16)(0.0f);
        __builtin_amdgcn_s_setprio(1);
        #pragma unroll
        for (int ks = 0; ks < 16; ks++) {
            bf16x8 a = *(const bf16x8*)(w1b + (ks << 10));
            acc1 = __builtin_amdgcn_mfma_f32_32x32x16_bf16(a, xr[ks], acc1, 0, 0, 0);
        }
        __builtin_amdgcn_s_setprio(0);

        // bias + relu, pack to bf16 pairs, permlane half-swap -> B-frags in regs
        float h[16];
        #pragma unroll
        for (int r = 0; r < 16; r++) {
            int fl = (wc << 5) + (r & 3) + ((r >> 2) << 3) + (hi << 2);
            h[r] = fmaxf(acc1[r] + b1s[(ch << 6) + fl], 0.f);
        }
        u32 w[8];
        #pragma unroll
        for (int t = 0; t < 8; t++)
            asm("v_cvt_pk_bf16_f32 %0, %1, %2" : "=v"(w[t]) : "v"(h[2 * t]), "v"(h[2 * t + 1]));
        asm volatile("v_permlane32_swap_b32 %0, %1" : "+v"(w[0]), "+v"(w[2]));
        asm volatile("v_permlane32_swap_b32 %0, %1" : "+v"(w[1]), "+v"(w[3]));
        asm volatile("v_permlane32_swap_b32 %0, %1" : "+v"(w[4]), "+v"(w[6]));
        asm volatile("v_permlane32_swap_b32 %0, %1" : "+v"(w[5]), "+v"(w[7]));
        union { u32x4 u; bf16x8 v; } fr0, fr1;
        fr0.u = (u32x4){w[0], w[1], w[2], w[3]};
        fr1.u = (u32x4){w[4], w[5], w[6], w[7]};

        // ---- phase 2 (K-split): acc2[ct] += W2frag(ct, 2wc+s) x Hfrag(s) ----
        __builtin_amdgcn_s_setprio(1);
        #pragma unroll
        for (int s = 0; s < 2; s++) {
            bf16x8 bh = s ? fr1.v : fr0.v;
            const char* w2p = w2b + (((wc << 1) + s) << 10);
            #pragma unroll
            for (int ct = 0; ct < 8; ct++) {
                bf16x8 a = *(const bf16x8*)(w2p + (ct << 12));
                acc2[ct] = __builtin_amdgcn_mfma_f32_32x32x16_bf16(a, bh, acc2[ct], 0, 0, 0);
            }
        }
        __builtin_amdgcn_s_setprio(0);

        // prefetch chunk ch+2 into the buffer just consumed
        if (ch + 2 < NCH) {
            #pragma unroll
            for (int i = 0; i < 4; i++) {
                int idx = (wid << 2) + i;
                int f = ((ch + 2) << 6) + ((idx >> 4) << 5) + (lane & 31);
                gload16(w1e + ((size_t)f << 8) + ((idx & 15) << 4) + (hi << 3),
                        smem + (cur << 15) + (idx << 10));
            }
            #pragma unroll
            for (int i = 0; i < 4; i++) {
                int idx = (wid << 2) + i;
                int c = ((idx >> 2) << 5) + (lane & 31);
                gload16(w2e + ((size_t)c << 10) + ((ch + 2) << 6) + ((idx & 3) << 4) + (hi << 3),
                        smem + W2S_OFF + (cur << 15) + (idx << 10));
            }
        }
    }

    // ---- cross-wc pair reduction via LDS (static acc2 indices only) ----
    __syncthreads();   // all chunk reads done; smem reusable
    float* red = (float*)smem;
    float* myslot = red + (wid << 12);            // 16KB per wave
    if (wc == 0) { STORE_HALF(4) } else { STORE_HALF(0) }
    __syncthreads();
    float* pslot = red + ((wid ^ 1) << 12);
    if (wc == 0) { REDUCE_HALF(0) } else { REDUCE_HALF(4) }

    int m = (wr << 5) + (lane & 31);
    if (m < rows) {
        if (MODE == 0) {
            float* yr = ybuf + ((size_t)(base + m) << 8);
            if (wc == 0) { WRITE_Y(0) } else { WRITE_Y(4) }
        } else {
            float wgt_m = s_w[m];
            float* orow = out + ((size_t)s_tok[m] << 8);
            if (wc == 0) { WRITE_ATOMIC(0) } else { WRITE_ATOMIC(4) }
        }
    }
}

__global__ __launch_bounds__(256) void combine_kernel(
    const float* __restrict__ ybuf, const int* __restrict__ tidx,
    const float* __restrict__ tw, const int* __restrict__ pairpos,
    const float* __restrict__ b2, float* __restrict__ out)
{
    int idx = blockIdx.x * 256 + threadIdx.x;
    int n = idx >> 6;
    int q = (idx & 63) << 2;
    int e0 = tidx[2 * n], e1 = tidx[2 * n + 1];
    float w0 = tw[2 * n], w1 = tw[2 * n + 1];
    int p0 = pairpos[2 * n], p1 = pairpos[2 * n + 1];
    float4 y0 = *(const float4*)(ybuf + ((size_t)p0 << 8) + q);
    float4 y1 = *(const float4*)(ybuf + ((size_t)p1 << 8) + q);
    float4 c0 = *(const float4*)(b2 + (e0 << 8) + q);
    float4 c1 = *(const float4*)(b2 + (e1 << 8) + q);
    float4 o;
    o.x = w0 * (y0.x + c0.x) + w1 * (y1.x + c1.x);
    o.y = w0 * (y0.y + c0.y) + w1 * (y1.y + c1.y);
    o.z = w0 * (y0.z + c0.z) + w1 * (y1.z + c1.z);
    o.w = w0 * (y0.w + c0.w) + w1 * (y1.w + c1.w);
    *(float4*)(out + ((size_t)n << 8) + q) = o;
}

extern "C" void kernel_launch(void* const* d_in, const int* in_sizes, int n_in,
                              void* d_out, int out_size, void* d_ws, size_t ws_size,
                              hipStream_t stream)
{
    const float* x   = (const float*)d_in[0];
    const float* gW  = (const float*)d_in[1];
    const float* gb  = (const float*)d_in[2];
    const float* W1  = (const float*)d_in[3];
    const float* b1  = (const float*)d_in[4];
    const float* W2  = (const float*)d_in[5];
    const float* b2  = (const float*)d_in[6];
    float* out = (float*)d_out;

    char* ws = (char*)d_ws;
    int*   topk_idx = (int*)(ws + 0);
    float* topk_w   = (float*)(ws + 262144);
    int*   tok      = (int*)(ws + 524288);
    float* wgt      = (float*)(ws + 786432);
    int*   pairpos  = (int*)(ws + 1048576);
    int*   counts   = (int*)(ws + 1310720);
    int*   fill     = (int*)(ws + 1310784);
    int*   offs     = (int*)(ws + 1310848);
    int*   tp       = (int*)(ws + 1310916);

    const size_t XB_OFF  = 2097152;
    const size_t W1T_OFF = 18874368;
    const size_t W2T_OFF = 27262976;
    const size_t Y_OFF   = 35651584;
    const size_t WS_FULL = Y_OFF + (size_t)2 * N_TOK * C_DIM * 4;

    u16* xb  = (u16*)(ws + XB_OFF);
    u16* w1t = (u16*)(ws + W1T_OFF);
    u16* w2t = (u16*)(ws + W2T_OFF);
    float* ybuf = (float*)(ws + Y_OFF);

    int mode = (ws_size >= WS_FULL) ? 0 : 1;

    hipMemsetAsync(d_out, 0, (size_t)(N_TOK * C_DIM + 1) * sizeof(float), stream);
    hipMemsetAsync(counts, 0, 2 * E_NUM * sizeof(int), stream);

    float* ent_out = out + (size_t)N_TOK * C_DIM;

    gate_kernel<<<N_TOK / 64, 256, 0, stream>>>(x, gW, gb, ent_out,
                                                topk_idx, topk_w, counts, xb);
    prefix_kernel<<<1, 64, 0, stream>>>(counts, offs, tp);
    scatter_kernel<<<N_TOK / 256, 256, 0, stream>>>(topk_idx, topk_w, offs,
                                                    fill, tok, wgt, pairpos);
    tcvt_kernel<<<dim3(E_NUM, C_DIM / 64, F_DIM / 64), 256, 0, stream>>>(W1, w1t, C_DIM, F_DIM);
    tcvt_kernel<<<dim3(E_NUM, F_DIM / 64, C_DIM / 64), 256, 0, stream>>>(W2, w2t, F_DIM, C_DIM);

    if (mode == 0) {
        ffn_mfma<0><<<544, 512, 0, stream>>>(xb, w1t, w2t, b1, b2, tok, wgt,
                                             offs, tp, ybuf, out);
        combine_kernel<<<N_TOK * 64 / 256, 256, 0, stream>>>(ybuf, topk_idx,
                                                             topk_w, pairpos, b2, out);
    } else {
        ffn_mfma<1><<<544, 512, 0, stream>>>(xb, w1t, w2t, b1, b2, tok, wgt,
                                             offs, tp, ybuf, out);
    }
}

// Round 6
// 259.400 us; speedup vs baseline: 1.0477x; 1.0477x over previous
//
#include <hip/hip_runtime.h>
#include <hip/hip_bf16.h>
#include <math.h>

#define N_TOK 32768
#define C_DIM 256
#define F_DIM 1024
#define E_NUM 16
#define TILE_R 128
#define NCH 16

typedef unsigned short u16;
typedef unsigned int u32;
typedef __attribute__((ext_vector_type(4))) u16 u16x4;
typedef __attribute__((ext_vector_type(8))) u16 u16x8;
typedef __attribute__((ext_vector_type(8))) short bf16x8;
typedef __attribute__((ext_vector_type(4))) u32 u32x4;
typedef __attribute__((ext_vector_type(4))) float f32x4;
typedef __attribute__((ext_vector_type(16))) float f32x16;

#define AS1 __attribute__((address_space(1)))
#define AS3 __attribute__((address_space(3)))

// async global->LDS: HW writes wave-uniform LDS base + lane*16
__device__ __forceinline__ void gload16(const void* g, void* lds) {
    __builtin_amdgcn_global_load_lds((const AS1 u32*)(uintptr_t)g,
                                     (AS3 u32*)(u32)(uintptr_t)lds, 16, 0, 0);
}

__device__ __forceinline__ u16 f2bf(float f) {
    union { float f; u32 u; } v; v.f = f;
    u32 r = v.u + 0x7fffu + ((v.u >> 16) & 1u);   // RNE
    return (u16)(r >> 16);
}

// ---------------- workspace layout (bytes) ----------------
// 0        topk_idx int[2N]
// 262144   topk_w   f32[2N]
// 524288   tok      int[2N]
// 786432   wgt      f32[2N]
// 1048576  pairpos  int[2N]
// 1310720  counts[16] fill[16] offs[17] tp[17]
// 2097152  xb   bf16[N][C]
// 18874368 w1t  bf16[E][F][C]
// 27262976 w2t  bf16[E][C][F]
// 35651584 ybuf f32[2N][C]  (MODE 0 only)

// ---- gate: 64 tokens/block, 4 lanes/token, fused x->bf16 conversion ----
__global__ __launch_bounds__(256) void gate_kernel(
    const float* __restrict__ x, const float* __restrict__ gW,
    const float* __restrict__ gb, float* __restrict__ ent_out,
    int* __restrict__ tidx, float* __restrict__ tw, int* __restrict__ counts,
    u16* __restrict__ xb)
{
    __shared__ float gws[E_NUM * C_DIM];
    __shared__ float gbs[E_NUM];
    __shared__ float went[4];
    __shared__ int lc[E_NUM];
    int tid = threadIdx.x;

    for (int i = tid; i < E_NUM * C_DIM / 4; i += 256)
        ((float4*)gws)[i] = ((const float4*)gW)[i];
    if (tid < E_NUM) { gbs[tid] = gb[tid]; lc[tid] = 0; }
    __syncthreads();

    int tok = tid >> 2, q = tid & 3;
    int n = blockIdx.x * 64 + tok;
    const float* xr = x + (size_t)n * C_DIM;

    float4 xv[16];
    #pragma unroll
    for (int j = 0; j < 16; j++)
        xv[j] = *(const float4*)(xr + j * 16 + q * 4);

    #pragma unroll
    for (int j = 0; j < 16; j++) {
        u16x4 o;
        o[0] = f2bf(xv[j].x); o[1] = f2bf(xv[j].y);
        o[2] = f2bf(xv[j].z); o[3] = f2bf(xv[j].w);
        *(u16x4*)(xb + (size_t)n * C_DIM + j * 16 + q * 4) = o;
    }

    float lg[E_NUM];
    #pragma unroll
    for (int e = 0; e < E_NUM; e++) lg[e] = 0.f;
    #pragma unroll
    for (int j = 0; j < 16; j++) {
        #pragma unroll
        for (int e = 0; e < E_NUM; e++) {
            float4 g = *(const float4*)(gws + e * C_DIM + j * 16 + q * 4);
            lg[e] += xv[j].x * g.x + xv[j].y * g.y + xv[j].z * g.z + xv[j].w * g.w;
        }
    }
    #pragma unroll
    for (int e = 0; e < E_NUM; e++) {
        lg[e] += __shfl_xor(lg[e], 1);
        lg[e] += __shfl_xor(lg[e], 2);
        lg[e] += gbs[e];
    }

    float m = lg[0];
    #pragma unroll
    for (int e = 1; e < E_NUM; e++) m = fmaxf(m, lg[e]);
    float s = 0.f, ex[E_NUM];
    #pragma unroll
    for (int e = 0; e < E_NUM; e++) { ex[e] = __expf(lg[e] - m); s += ex[e]; }
    float inv = 1.f / s;
    float ent = 0.f;
    #pragma unroll
    for (int e = 0; e < E_NUM; e++) {
        float p = ex[e] * inv;
        ent -= p * logf(p + 1e-8f);
    }

    float v0 = -1e30f, v1 = -1e30f;
    int i0 = 0, i1 = 0;
    #pragma unroll
    for (int e = 0; e < E_NUM; e++) {
        float l = lg[e];
        if (l > v0) { v1 = v0; i1 = i0; v0 = l; i0 = e; }
        else if (l > v1) { v1 = l; i1 = e; }
    }
    if (q == 0) {
        float w1e = __expf(v1 - v0);
        float z = 1.f + w1e;
        tidx[2 * n] = i0; tidx[2 * n + 1] = i1;
        tw[2 * n] = 1.f / z; tw[2 * n + 1] = w1e / z;
        atomicAdd(&lc[i0], 1);
        atomicAdd(&lc[i1], 1);
    }

    float v = ent;   // 4x duplicated per token -> scale 1/(4N)
    for (int off = 32; off > 0; off >>= 1) v += __shfl_down(v, off);
    int wid = tid >> 6, lane = tid & 63;
    if (lane == 0) went[wid] = v;
    __syncthreads();
    if (tid == 0)
        atomicAdd(ent_out, (went[0] + went[1] + went[2] + went[3]) * (1.0f / (4.0f * N_TOK)));
    if (tid < E_NUM && lc[tid]) atomicAdd(&counts[tid], lc[tid]);
}

__global__ void prefix_kernel(const int* __restrict__ counts,
                              int* __restrict__ offs, int* __restrict__ tp)
{
    if (threadIdx.x == 0 && blockIdx.x == 0) {
        int o = 0, t = 0;
        offs[0] = 0; tp[0] = 0;
        for (int e = 0; e < E_NUM; e++) {
            o += counts[e];
            t += (counts[e] + TILE_R - 1) / TILE_R;
            offs[e + 1] = o;
            tp[e + 1] = t;
        }
    }
}

__global__ __launch_bounds__(256) void scatter_kernel(
    const int* __restrict__ tidx, const float* __restrict__ tw,
    const int* __restrict__ offs, int* __restrict__ fill,
    int* __restrict__ tok, float* __restrict__ wgt, int* __restrict__ pairpos)
{
    __shared__ int lc[E_NUM], lbase[E_NUM];
    int tid = threadIdx.x;
    if (tid < E_NUM) lc[tid] = 0;
    __syncthreads();
    int n = blockIdx.x * 256 + tid;
    int e0 = tidx[2 * n], e1 = tidx[2 * n + 1];
    int r0 = atomicAdd(&lc[e0], 1);
    int r1 = atomicAdd(&lc[e1], 1);
    __syncthreads();
    if (tid < E_NUM) lbase[tid] = offs[tid] + atomicAdd(&fill[tid], lc[tid]);
    __syncthreads();
    int p0 = lbase[e0] + r0, p1 = lbase[e1] + r1;
    tok[p0] = n; wgt[p0] = tw[2 * n];     pairpos[2 * n] = p0;
    tok[p1] = n; wgt[p1] = tw[2 * n + 1]; pairpos[2 * n + 1] = p1;
}

// per-expert transpose+convert: src f32 [R][Cc] -> dst bf16 [Cc][R]
__global__ __launch_bounds__(256) void tcvt_kernel(
    const float* __restrict__ src, u16* __restrict__ dst, int R, int Cc)
{
    __shared__ float t[64][65];
    int e = blockIdx.x;
    int r0 = blockIdx.y << 6, c0 = blockIdx.z << 6;
    const float* s = src + (size_t)e * R * Cc;
    u16* d = dst + (size_t)e * R * Cc;
    int tid = threadIdx.x;
    int rr = tid >> 4, cc = (tid & 15) << 2;
    #pragma unroll
    for (int it = 0; it < 4; it++) {
        float4 v = *(const float4*)(s + (size_t)(r0 + rr + it * 16) * Cc + c0 + cc);
        t[rr + it * 16][cc] = v.x; t[rr + it * 16][cc + 1] = v.y;
        t[rr + it * 16][cc + 2] = v.z; t[rr + it * 16][cc + 3] = v.w;
    }
    __syncthreads();
    int cr = tid >> 3, rq = (tid & 7) << 3;
    #pragma unroll
    for (int it = 0; it < 2; it++) {
        int c = cr + it * 32;
        u16x8 o;
        #pragma unroll
        for (int j = 0; j < 8; j++) o[j] = f2bf(t[rq + j][c]);
        *(u16x8*)(d + (size_t)(c0 + c) * R + r0 + rq) = o;
    }
}

// ---- FFN: 128-token tile, 8 waves, 32x32x16 MFMA ----
// LDS: w1s dbuf 2x32K @0 | w2s dbuf 2x32K @65536 | b1s 4K @131072 | tok/w
// x fragments live in registers (loaded once via LDS prologue).
// K-loop: counted vmcnt(8) + raw s_barrier (T4) -- prefetch distance 2,
// never drains vmcnt to 0 inside the loop.
#define W2S_OFF 65536
#define B1S_OFF 131072

#define STORE_HALF(B)                                                         \
    _Pragma("unroll")                                                         \
    for (int j = 0; j < 4; j++) {                                             \
        _Pragma("unroll")                                                     \
        for (int rq = 0; rq < 4; rq++) {                                      \
            float4 v = {acc2[(B) + j][4 * rq],     acc2[(B) + j][4 * rq + 1], \
                        acc2[(B) + j][4 * rq + 2], acc2[(B) + j][4 * rq + 3]};\
            *(float4*)(myslot + ((((j << 2) + rq) << 6) + lane) * 4) = v;     \
        }                                                                     \
    }

#define REDUCE_HALF(B)                                                        \
    _Pragma("unroll")                                                         \
    for (int j = 0; j < 4; j++) {                                             \
        _Pragma("unroll")                                                     \
        for (int rq = 0; rq < 4; rq++) {                                      \
            float4 v = *(const float4*)(pslot + ((((j << 2) + rq) << 6) + lane) * 4); \
            acc2[(B) + j][4 * rq]     += v.x;                                 \
            acc2[(B) + j][4 * rq + 1] += v.y;                                 \
            acc2[(B) + j][4 * rq + 2] += v.z;                                 \
            acc2[(B) + j][4 * rq + 3] += v.w;                                 \
        }                                                                     \
    }

#define WRITE_Y(B)                                                            \
    _Pragma("unroll")                                                         \
    for (int j = 0; j < 4; j++) {                                             \
        _Pragma("unroll")                                                     \
        for (int rq = 0; rq < 4; rq++) {                                      \
            int c = (((B) + j) << 5) + (rq << 3) + (hi << 2);                 \
            float4 v = {acc2[(B) + j][4 * rq],     acc2[(B) + j][4 * rq + 1], \
                        acc2[(B) + j][4 * rq + 2], acc2[(B) + j][4 * rq + 3]};\
            *(float4*)(yr + c) = v;                                           \
        }                                                                     \
    }

#define WRITE_ATOMIC(B)                                                       \
    _Pragma("unroll")                                                         \
    for (int j = 0; j < 4; j++) {                                             \
        _Pragma("unroll")                                                     \
        for (int rq = 0; rq < 4; rq++) {                                      \
            int c = (((B) + j) << 5) + (rq << 3) + (hi << 2);                 \
            _Pragma("unroll")                                                 \
            for (int l = 0; l < 4; l++)                                       \
                atomicAdd(&orow[c + l],                                       \
                          wgt_m * (acc2[(B) + j][4 * rq + l] + b2e[c + l]));  \
        }                                                                     \
    }

template <int MODE>
__global__ __launch_bounds__(512, 2) void ffn_mfma(
    const u16* __restrict__ xb, const u16* __restrict__ w1t,
    const u16* __restrict__ w2t, const float* __restrict__ b1,
    const float* __restrict__ b2, const int* __restrict__ tok,
    const float* __restrict__ wgt, const int* __restrict__ offs,
    const int* __restrict__ tp, float* __restrict__ ybuf,
    float* __restrict__ out)
{
    __shared__ __align__(1024) char smem[136192];
    int* s_tok = (int*)(smem + 135168);
    float* s_w = (float*)(smem + 135680);
    float* b1s = (float*)(smem + B1S_OFF);

    int b = blockIdx.x;
    if (b >= tp[E_NUM]) return;
    int e = 0;
    while (b >= tp[e + 1]) e++;
    int base = offs[e] + ((b - tp[e]) << 7);
    int rows = offs[e + 1] - base; if (rows > TILE_R) rows = TILE_R;

    int tid = threadIdx.x;
    int lane = tid & 63, wid = tid >> 6;
    int hi = lane >> 5;
    int wr = wid >> 1, wc = wid & 1;

    const u16* w1e = w1t + (size_t)e * (F_DIM * C_DIM);   // [F][C]
    const u16* w2e = w2t + (size_t)e * (C_DIM * F_DIM);   // [C][F]
    const float* b1e = b1 + e * F_DIM;
    const float* b2e = b2 + e * C_DIM;

    if (tid < TILE_R) {
        int src = (tid < rows) ? base + tid : base;
        s_tok[tid] = tok[src];
        s_w[tid] = (tid < rows) ? wgt[src] : 0.f;
    }
    if (tid < 256) ((float4*)b1s)[tid] = ((const float4*)b1e)[tid];
    __syncthreads();

    // ---- prologue: stage x tile through LDS (w1s region), hoist to regs ----
    #pragma unroll
    for (int i = 0; i < 8; i++) {
        int idx = (wid << 3) + i;
        int row = ((idx >> 4) << 5) + (lane & 31);
        const u16* src = xb + ((size_t)s_tok[row] << 8) + ((idx & 15) << 4) + (hi << 3);
        gload16(src, smem + (idx << 10));
    }
    __syncthreads();   // x staged (vmcnt(0) drain here is fine, once)

    bf16x8 xr[16];     // this wave's m-tile (wr), all 16 k-slices: 64 VGPR
    #pragma unroll
    for (int ks = 0; ks < 16; ks++)
        xr[ks] = *(const bf16x8*)(smem + (wr << 14) + (ks << 10) + (lane << 4));
    __syncthreads();   // xr in regs; w1s region free for dbuf

    // stage chunks 0 and 1 into the two buffers (8 loads/wave per chunk)
    #pragma unroll
    for (int cur = 0; cur < 2; cur++) {
        #pragma unroll
        for (int i = 0; i < 4; i++) {
            int idx = (wid << 2) + i;
            int f = (cur << 6) + ((idx >> 4) << 5) + (lane & 31);
            gload16(w1e + ((size_t)f << 8) + ((idx & 15) << 4) + (hi << 3),
                    smem + (cur << 15) + (idx << 10));
        }
        #pragma unroll
        for (int i = 0; i < 4; i++) {
            int idx = (wid << 2) + i;
            int c = ((idx >> 2) << 5) + (lane & 31);
            gload16(w2e + ((size_t)c << 10) + (cur << 6) + ((idx & 3) << 4) + (hi << 3),
                    smem + W2S_OFF + (cur << 15) + (idx << 10));
        }
    }

    f32x16 acc2[8];
    #pragma unroll
    for (int ct = 0; ct < 8; ct++) acc2[ct] = (f32x16)(0.0f);

    for (int ch = 0; ch < NCH; ch++) {
        int cur = ch & 1;
        // counted drain: this chunk's 8 loads done; next chunk's 8 stay in flight
        asm volatile("s_waitcnt vmcnt(8)" ::: "memory");
        __builtin_amdgcn_s_barrier();          // all waves' data for ch in LDS
        __builtin_amdgcn_sched_barrier(0);

        const char* w1b = smem + (cur << 15) + (wc << 14) + (lane << 4);
        const char* w2b = smem + W2S_OFF + (cur << 15) + (lane << 4);

        // ---- phase 1: Ht = W1 x X^T (swapped) -> D[f][m], col=m=lane&31 ----
        f32x16 acc1 = (f32x16)(0.0f);
        __builtin_amdgcn_s_setprio(1);
        #pragma unroll
        for (int ks = 0; ks < 16; ks++) {
            bf16x8 a = *(const bf16x8*)(w1b + (ks << 10));
            acc1 = __builtin_amdgcn_mfma_f32_32x32x16_bf16(a, xr[ks], acc1, 0, 0, 0);
        }
        __builtin_amdgcn_s_setprio(0);

        // bias + relu, pack to bf16 pairs, permlane half-swap -> B-frags in regs
        float h[16];
        #pragma unroll
        for (int r = 0; r < 16; r++) {
            int fl = (wc << 5) + (r & 3) + ((r >> 2) << 3) + (hi << 2);
            h[r] = fmaxf(acc1[r] + b1s[(ch << 6) + fl], 0.f);
        }
        u32 w[8];
        #pragma unroll
        for (int t = 0; t < 8; t++)
            asm("v_cvt_pk_bf16_f32 %0, %1, %2" : "=v"(w[t]) : "v"(h[2 * t]), "v"(h[2 * t + 1]));
        asm volatile("v_permlane32_swap_b32 %0, %1" : "+v"(w[0]), "+v"(w[2]));
        asm volatile("v_permlane32_swap_b32 %0, %1" : "+v"(w[1]), "+v"(w[3]));
        asm volatile("v_permlane32_swap_b32 %0, %1" : "+v"(w[4]), "+v"(w[6]));
        asm volatile("v_permlane32_swap_b32 %0, %1" : "+v"(w[5]), "+v"(w[7]));
        union { u32x4 u; bf16x8 v; } fr0, fr1;
        fr0.u = (u32x4){w[0], w[1], w[2], w[3]};
        fr1.u = (u32x4){w[4], w[5], w[6], w[7]};

        // ---- phase 2 (K-split): acc2[ct] += W2frag(ct, 2wc+s) x Hfrag(s) ----
        __builtin_amdgcn_s_setprio(1);
        #pragma unroll
        for (int s = 0; s < 2; s++) {
            bf16x8 bh = s ? fr1.v : fr0.v;
            const char* w2p = w2b + (((wc << 1) + s) << 10);
            #pragma unroll
            for (int ct = 0; ct < 8; ct++) {
                bf16x8 a = *(const bf16x8*)(w2p + (ct << 12));
                acc2[ct] = __builtin_amdgcn_mfma_f32_32x32x16_bf16(a, bh, acc2[ct], 0, 0, 0);
            }
        }
        __builtin_amdgcn_s_setprio(0);
        __builtin_amdgcn_sched_barrier(0);
        __builtin_amdgcn_s_barrier();          // all waves done reading buf cur

        // prefetch chunk (ch+2)&15 into buffer cur. Wrap keeps the vmcnt
        // count uniform; wrapped (junk) loads are drained after the loop
        // and never read.
        {
            int chn = (ch + 2) & 15;
            #pragma unroll
            for (int i = 0; i < 4; i++) {
                int idx = (wid << 2) + i;
                int f = (chn << 6) + ((idx >> 4) << 5) + (lane & 31);
                gload16(w1e + ((size_t)f << 8) + ((idx & 15) << 4) + (hi << 3),
                        smem + (cur << 15) + (idx << 10));
            }
            #pragma unroll
            for (int i = 0; i < 4; i++) {
                int idx = (wid << 2) + i;
                int c = ((idx >> 2) << 5) + (lane & 31);
                gload16(w2e + ((size_t)c << 10) + (chn << 6) + ((idx & 3) << 4) + (hi << 3),
                        smem + W2S_OFF + (cur << 15) + (idx << 10));
            }
        }
    }

    // drain wrapped junk prefetches before reusing LDS for the reduction
    asm volatile("s_waitcnt vmcnt(0)" ::: "memory");
    __syncthreads();

    // ---- cross-wc pair reduction via LDS (static acc2 indices only) ----
    float* red = (float*)smem;
    float* myslot = red + (wid << 12);            // 16KB per wave
    if (wc == 0) { STORE_HALF(4) } else { STORE_HALF(0) }
    __syncthreads();
    float* pslot = red + ((wid ^ 1) << 12);
    if (wc == 0) { REDUCE_HALF(0) } else { REDUCE_HALF(4) }

    int m = (wr << 5) + (lane & 31);
    if (m < rows) {
        if (MODE == 0) {
            float* yr = ybuf + ((size_t)(base + m) << 8);
            if (wc == 0) { WRITE_Y(0) } else { WRITE_Y(4) }
        } else {
            float wgt_m = s_w[m];
            float* orow = out + ((size_t)s_tok[m] << 8);
            if (wc == 0) { WRITE_ATOMIC(0) } else { WRITE_ATOMIC(4) }
        }
    }
}

__global__ __launch_bounds__(256) void combine_kernel(
    const float* __restrict__ ybuf, const int* __restrict__ tidx,
    const float* __restrict__ tw, const int* __restrict__ pairpos,
    const float* __restrict__ b2, float* __restrict__ out)
{
    int idx = blockIdx.x * 256 + threadIdx.x;
    int n = idx >> 6;
    int q = (idx & 63) << 2;
    int e0 = tidx[2 * n], e1 = tidx[2 * n + 1];
    float w0 = tw[2 * n], w1 = tw[2 * n + 1];
    int p0 = pairpos[2 * n], p1 = pairpos[2 * n + 1];
    float4 y0 = *(const float4*)(ybuf + ((size_t)p0 << 8) + q);
    float4 y1 = *(const float4*)(ybuf + ((size_t)p1 << 8) + q);
    float4 c0 = *(const float4*)(b2 + (e0 << 8) + q);
    float4 c1 = *(const float4*)(b2 + (e1 << 8) + q);
    float4 o;
    o.x = w0 * (y0.x + c0.x) + w1 * (y1.x + c1.x);
    o.y = w0 * (y0.y + c0.y) + w1 * (y1.y + c1.y);
    o.z = w0 * (y0.z + c0.z) + w1 * (y1.z + c1.z);
    o.w = w0 * (y0.w + c0.w) + w1 * (y1.w + c1.w);
    *(float4*)(out + ((size_t)n << 8) + q) = o;
}

extern "C" void kernel_launch(void* const* d_in, const int* in_sizes, int n_in,
                              void* d_out, int out_size, void* d_ws, size_t ws_size,
                              hipStream_t stream)
{
    const float* x   = (const float*)d_in[0];
    const float* gW  = (const float*)d_in[1];
    const float* gb  = (const float*)d_in[2];
    const float* W1  = (const float*)d_in[3];
    const float* b1  = (const float*)d_in[4];
    const float* W2  = (const float*)d_in[5];
    const float* b2  = (const float*)d_in[6];
    float* out = (float*)d_out;

    char* ws = (char*)d_ws;
    int*   topk_idx = (int*)(ws + 0);
    float* topk_w   = (float*)(ws + 262144);
    int*   tok      = (int*)(ws + 524288);
    float* wgt      = (float*)(ws + 786432);
    int*   pairpos  = (int*)(ws + 1048576);
    int*   counts   = (int*)(ws + 1310720);
    int*   fill     = (int*)(ws + 1310784);
    int*   offs     = (int*)(ws + 1310848);
    int*   tp       = (int*)(ws + 1310916);

    const size_t XB_OFF  = 2097152;
    const size_t W1T_OFF = 18874368;
    const size_t W2T_OFF = 27262976;
    const size_t Y_OFF   = 35651584;
    const size_t WS_FULL = Y_OFF + (size_t)2 * N_TOK * C_DIM * 4;

    u16* xb  = (u16*)(ws + XB_OFF);
    u16* w1t = (u16*)(ws + W1T_OFF);
    u16* w2t = (u16*)(ws + W2T_OFF);
    float* ybuf = (float*)(ws + Y_OFF);

    int mode = (ws_size >= WS_FULL) ? 0 : 1;

    hipMemsetAsync(d_out, 0, (size_t)(N_TOK * C_DIM + 1) * sizeof(float), stream);
    hipMemsetAsync(counts, 0, 2 * E_NUM * sizeof(int), stream);

    float* ent_out = out + (size_t)N_TOK * C_DIM;

    gate_kernel<<<N_TOK / 64, 256, 0, stream>>>(x, gW, gb, ent_out,
                                                topk_idx, topk_w, counts, xb);
    prefix_kernel<<<1, 64, 0, stream>>>(counts, offs, tp);
    scatter_kernel<<<N_TOK / 256, 256, 0, stream>>>(topk_idx, topk_w, offs,
                                                    fill, tok, wgt, pairpos);
    tcvt_kernel<<<dim3(E_NUM, C_DIM / 64, F_DIM / 64), 256, 0, stream>>>(W1, w1t, C_DIM, F_DIM);
    tcvt_kernel<<<dim3(E_NUM, F_DIM / 64, C_DIM / 64), 256, 0, stream>>>(W2, w2t, F_DIM, C_DIM);

    if (mode == 0) {
        ffn_mfma<0><<<544, 512, 0, stream>>>(xb, w1t, w2t, b1, b2, tok, wgt,
                                             offs, tp, ybuf, out);
        combine_kernel<<<N_TOK * 64 / 256, 256, 0, stream>>>(ybuf, topk_idx,
                                                             topk_w, pairpos, b2, out);
    } else {
        ffn_mfma<1><<<544, 512, 0, stream>>>(xb, w1t, w2t, b1, b2, tok, wgt,
                                             offs, tp, ybuf, out);
    }
}

// Round 7
// 222.238 us; speedup vs baseline: 1.2229x; 1.1672x over previous
//
#include <hip/hip_runtime.h>
#include <hip/hip_bf16.h>
#include <math.h>

#define N_TOK 32768
#define C_DIM 256
#define F_DIM 1024
#define E_NUM 16
#define TILE_R 128
#define NCH 16

typedef unsigned short u16;
typedef unsigned int u32;
typedef __attribute__((ext_vector_type(4))) u16 u16x4;
typedef __attribute__((ext_vector_type(8))) u16 u16x8;
typedef __attribute__((ext_vector_type(8))) short bf16x8;
typedef __attribute__((ext_vector_type(4))) u32 u32x4;
typedef __attribute__((ext_vector_type(16))) float f32x16;

#define AS1 __attribute__((address_space(1)))
#define AS3 __attribute__((address_space(3)))

// async global->LDS (prologue only): LDS dest = wave-uniform base + lane*16
__device__ __forceinline__ void gload16(const void* g, void* lds) {
    __builtin_amdgcn_global_load_lds((const AS1 u32*)(uintptr_t)g,
                                     (AS3 u32*)(u32)(uintptr_t)lds, 16, 0, 0);
}

__device__ __forceinline__ u16 f2bf(float f) {
    union { float f; u32 u; } v; v.f = f;
    u32 r = v.u + 0x7fffu + ((v.u >> 16) & 1u);   // RNE
    return (u16)(r >> 16);
}

// ---------------- workspace layout (bytes) ----------------
// 0        topk_idx int[2N]
// 262144   topk_w   f32[2N]
// 524288   tok      int[2N]
// 786432   wgt      f32[2N]
// 1048576  pairpos  int[2N]
// 1310720  counts[16] fill[16] offs[17] tp[17]
// 2097152  xb   bf16[N][C]
// 18874368 w1t  bf16[E][F][C]
// 27262976 w2t  bf16[E][C][F]
// 35651584 ybuf f32[2N][C]  (MODE 0 only)

// ---- gate: 64 tokens/block, 4 lanes/token, fused x->bf16 conversion ----
__global__ __launch_bounds__(256) void gate_kernel(
    const float* __restrict__ x, const float* __restrict__ gW,
    const float* __restrict__ gb, float* __restrict__ ent_out,
    int* __restrict__ tidx, float* __restrict__ tw, int* __restrict__ counts,
    u16* __restrict__ xb)
{
    __shared__ float gws[E_NUM * C_DIM];
    __shared__ float gbs[E_NUM];
    __shared__ float went[4];
    __shared__ int lc[E_NUM];
    int tid = threadIdx.x;

    for (int i = tid; i < E_NUM * C_DIM / 4; i += 256)
        ((float4*)gws)[i] = ((const float4*)gW)[i];
    if (tid < E_NUM) { gbs[tid] = gb[tid]; lc[tid] = 0; }
    __syncthreads();

    int tok = tid >> 2, q = tid & 3;
    int n = blockIdx.x * 64 + tok;
    const float* xr = x + (size_t)n * C_DIM;

    float4 xv[16];
    #pragma unroll
    for (int j = 0; j < 16; j++)
        xv[j] = *(const float4*)(xr + j * 16 + q * 4);

    #pragma unroll
    for (int j = 0; j < 16; j++) {
        u16x4 o;
        o[0] = f2bf(xv[j].x); o[1] = f2bf(xv[j].y);
        o[2] = f2bf(xv[j].z); o[3] = f2bf(xv[j].w);
        *(u16x4*)(xb + (size_t)n * C_DIM + j * 16 + q * 4) = o;
    }

    float lg[E_NUM];
    #pragma unroll
    for (int e = 0; e < E_NUM; e++) lg[e] = 0.f;
    #pragma unroll
    for (int j = 0; j < 16; j++) {
        #pragma unroll
        for (int e = 0; e < E_NUM; e++) {
            float4 g = *(const float4*)(gws + e * C_DIM + j * 16 + q * 4);
            lg[e] += xv[j].x * g.x + xv[j].y * g.y + xv[j].z * g.z + xv[j].w * g.w;
        }
    }
    #pragma unroll
    for (int e = 0; e < E_NUM; e++) {
        lg[e] += __shfl_xor(lg[e], 1);
        lg[e] += __shfl_xor(lg[e], 2);
        lg[e] += gbs[e];
    }

    float m = lg[0];
    #pragma unroll
    for (int e = 1; e < E_NUM; e++) m = fmaxf(m, lg[e]);
    float s = 0.f, ex[E_NUM];
    #pragma unroll
    for (int e = 0; e < E_NUM; e++) { ex[e] = __expf(lg[e] - m); s += ex[e]; }
    float inv = 1.f / s;
    float ent = 0.f;
    #pragma unroll
    for (int e = 0; e < E_NUM; e++) {
        float p = ex[e] * inv;
        ent -= p * logf(p + 1e-8f);
    }

    float v0 = -1e30f, v1 = -1e30f;
    int i0 = 0, i1 = 0;
    #pragma unroll
    for (int e = 0; e < E_NUM; e++) {
        float l = lg[e];
        if (l > v0) { v1 = v0; i1 = i0; v0 = l; i0 = e; }
        else if (l > v1) { v1 = l; i1 = e; }
    }
    if (q == 0) {
        float w1e = __expf(v1 - v0);
        float z = 1.f + w1e;
        tidx[2 * n] = i0; tidx[2 * n + 1] = i1;
        tw[2 * n] = 1.f / z; tw[2 * n + 1] = w1e / z;
        atomicAdd(&lc[i0], 1);
        atomicAdd(&lc[i1], 1);
    }

    float v = ent;   // 4x duplicated per token -> scale 1/(4N)
    for (int off = 32; off > 0; off >>= 1) v += __shfl_down(v, off);
    int wid = tid >> 6, lane = tid & 63;
    if (lane == 0) went[wid] = v;
    __syncthreads();
    if (tid == 0)
        atomicAdd(ent_out, (went[0] + went[1] + went[2] + went[3]) * (1.0f / (4.0f * N_TOK)));
    if (tid < E_NUM && lc[tid]) atomicAdd(&counts[tid], lc[tid]);
}

__global__ void prefix_kernel(const int* __restrict__ counts,
                              int* __restrict__ offs, int* __restrict__ tp)
{
    if (threadIdx.x == 0 && blockIdx.x == 0) {
        int o = 0, t = 0;
        offs[0] = 0; tp[0] = 0;
        for (int e = 0; e < E_NUM; e++) {
            o += counts[e];
            t += (counts[e] + TILE_R - 1) / TILE_R;
            offs[e + 1] = o;
            tp[e + 1] = t;
        }
    }
}

__global__ __launch_bounds__(256) void scatter_kernel(
    const int* __restrict__ tidx, const float* __restrict__ tw,
    const int* __restrict__ offs, int* __restrict__ fill,
    int* __restrict__ tok, float* __restrict__ wgt, int* __restrict__ pairpos)
{
    __shared__ int lc[E_NUM], lbase[E_NUM];
    int tid = threadIdx.x;
    if (tid < E_NUM) lc[tid] = 0;
    __syncthreads();
    int n = blockIdx.x * 256 + tid;
    int e0 = tidx[2 * n], e1 = tidx[2 * n + 1];
    int r0 = atomicAdd(&lc[e0], 1);
    int r1 = atomicAdd(&lc[e1], 1);
    __syncthreads();
    if (tid < E_NUM) lbase[tid] = offs[tid] + atomicAdd(&fill[tid], lc[tid]);
    __syncthreads();
    int p0 = lbase[e0] + r0, p1 = lbase[e1] + r1;
    tok[p0] = n; wgt[p0] = tw[2 * n];     pairpos[2 * n] = p0;
    tok[p1] = n; wgt[p1] = tw[2 * n + 1]; pairpos[2 * n + 1] = p1;
}

// per-expert transpose+convert: src f32 [R][Cc] -> dst bf16 [Cc][R]
__global__ __launch_bounds__(256) void tcvt_kernel(
    const float* __restrict__ src, u16* __restrict__ dst, int R, int Cc)
{
    __shared__ float t[64][65];
    int e = blockIdx.x;
    int r0 = blockIdx.y << 6, c0 = blockIdx.z << 6;
    const float* s = src + (size_t)e * R * Cc;
    u16* d = dst + (size_t)e * R * Cc;
    int tid = threadIdx.x;
    int rr = tid >> 4, cc = (tid & 15) << 2;
    #pragma unroll
    for (int it = 0; it < 4; it++) {
        float4 v = *(const float4*)(s + (size_t)(r0 + rr + it * 16) * Cc + c0 + cc);
        t[rr + it * 16][cc] = v.x; t[rr + it * 16][cc + 1] = v.y;
        t[rr + it * 16][cc + 2] = v.z; t[rr + it * 16][cc + 3] = v.w;
    }
    __syncthreads();
    int cr = tid >> 3, rq = (tid & 7) << 3;
    #pragma unroll
    for (int it = 0; it < 2; it++) {
        int c = cr + it * 32;
        u16x8 o;
        #pragma unroll
        for (int j = 0; j < 8; j++) o[j] = f2bf(t[rq + j][c]);
        *(u16x8*)(d + (size_t)(c0 + c) * R + r0 + rq) = o;
    }
}

// ---- FFN: 128-token tile, 8 waves, 32x32x16 MFMA, reg-staged pipeline ----
// LDS: stg dbuf [2][w1 32K | w2 32K] @0 (128K) | hs 16K @131072 |
//      b1s 4K @147456 | s_tok @151552 | s_w @152064
// x frags in regs (prologue); Ht partner-exchange via hs (no K-split,
// acc2 = 4 frags = 64 AGPR; no end reduction).
#define HS_OFF  131072
#define B1S_OFF 147456

template <int MODE>
__global__ __launch_bounds__(512, 2) void ffn_mfma(
    const u16* __restrict__ xb, const u16* __restrict__ w1t,
    const u16* __restrict__ w2t, const float* __restrict__ b1,
    const float* __restrict__ b2, const int* __restrict__ tok,
    const float* __restrict__ wgt, const int* __restrict__ offs,
    const int* __restrict__ tp, float* __restrict__ ybuf,
    float* __restrict__ out)
{
    __shared__ __align__(1024) char smem[152576];
    int* s_tok = (int*)(smem + 151552);
    float* s_w = (float*)(smem + 152064);
    float* b1s = (float*)(smem + B1S_OFF);

    int b = blockIdx.x;
    if (b >= tp[E_NUM]) return;
    int e = 0;
    while (b >= tp[e + 1]) e++;
    int base = offs[e] + ((b - tp[e]) << 7);
    int rows = offs[e + 1] - base; if (rows > TILE_R) rows = TILE_R;

    int tid = threadIdx.x;
    int lane = tid & 63, wid = tid >> 6;
    int hi = lane >> 5;
    int wr = wid >> 1, wc = wid & 1;

    const u16* w1e = w1t + (size_t)e * (F_DIM * C_DIM);   // [F][C]
    const u16* w2e = w2t + (size_t)e * (C_DIM * F_DIM);   // [C][F]
    const float* b1e = b1 + e * F_DIM;
    const float* b2e = b2 + e * C_DIM;

    if (tid < TILE_R) {
        int src = (tid < rows) ? base + tid : base;
        s_tok[tid] = tok[src];
        s_w[tid] = (tid < rows) ? wgt[src] : 0.f;
    }
    if (tid < 256) ((float4*)b1s)[tid] = ((const float4*)b1e)[tid];
    __syncthreads();

    // ---- prologue: stage x tile through LDS (stg region), hoist to regs ----
    #pragma unroll
    for (int i = 0; i < 8; i++) {
        int idx = (wid << 3) + i;
        int row = ((idx >> 4) << 5) + (lane & 31);
        gload16(xb + ((size_t)s_tok[row] << 8) + ((idx & 15) << 4) + (hi << 3),
                smem + (idx << 10));
    }
    __syncthreads();   // one-time vmcnt(0) drain, fine

    bf16x8 xr[16];     // this wave's m-tile (wr), 16 k-slices: 64 VGPR
    #pragma unroll
    for (int ks = 0; ks < 16; ks++)
        xr[ks] = *(const bf16x8*)(smem + (wr << 14) + (ks << 10) + (lane << 4));
    __syncthreads();   // xr in regs; stg region free

    // ---- stage chunk 0 via regs into buf 0 ----
    u32x4 sg[8];
    #pragma unroll
    for (int i = 0; i < 4; i++) {
        int idx = (wid << 2) + i;
        int f = ((idx >> 4) << 5) + (lane & 31);
        sg[i] = *(const u32x4*)(w1e + ((size_t)f << 8) + ((idx & 15) << 4) + (hi << 3));
        int c = ((idx >> 2) << 5) + (lane & 31);
        sg[4 + i] = *(const u32x4*)(w2e + ((size_t)c << 10) + ((idx & 3) << 4) + (hi << 3));
    }
    #pragma unroll
    for (int i = 0; i < 4; i++) {
        int idx = (wid << 2) + i;
        *(u32x4*)(smem + (idx << 10) + (lane << 4)) = sg[i];
        *(u32x4*)(smem + 32768 + (idx << 10) + (lane << 4)) = sg[4 + i];
    }

    f32x16 acc2[4];
    #pragma unroll
    for (int ct = 0; ct < 4; ct++) acc2[ct] = (f32x16)(0.0f);

    for (int ch = 0; ch < NCH; ch++) {
        int cur = ch & 1;
        const char* cbuf = smem + (cur << 16);

        // B0: buf[cur] writes visible (writers drained own lgkm first)
        asm volatile("s_waitcnt lgkmcnt(0)" ::: "memory");
        __builtin_amdgcn_s_barrier();
        __builtin_amdgcn_sched_barrier(0);

        // issue chunk ch+1 loads -> regs (waited only at the ds_write below)
        {
            int chn = ch + 1; if (chn == NCH) chn = NCH - 1;
            #pragma unroll
            for (int i = 0; i < 4; i++) {
                int idx = (wid << 2) + i;
                int f = (chn << 6) + ((idx >> 4) << 5) + (lane & 31);
                sg[i] = *(const u32x4*)(w1e + ((size_t)f << 8) + ((idx & 15) << 4) + (hi << 3));
                int c = ((idx >> 2) << 5) + (lane & 31);
                sg[4 + i] = *(const u32x4*)(w2e + ((size_t)c << 10) + (chn << 6) + ((idx & 3) << 4) + (hi << 3));
            }
        }

        // ---- phase 1: Ht = W1 x X^T -> D[f][m] for this wave's (wc,wr) ----
        const char* w1b = cbuf + (wc << 14) + (lane << 4);
        f32x16 acc1 = (f32x16)(0.0f);
        __builtin_amdgcn_s_setprio(1);
        #pragma unroll
        for (int ks = 0; ks < 16; ks++) {
            bf16x8 a = *(const bf16x8*)(w1b + (ks << 10));
            acc1 = __builtin_amdgcn_mfma_f32_32x32x16_bf16(a, xr[ks], acc1, 0, 0, 0);
        }
        __builtin_amdgcn_s_setprio(0);

        // bias + relu -> bf16 B-frags (k-slices 2wc, 2wc+1) in regs
        float h[16];
        #pragma unroll
        for (int r = 0; r < 16; r++) {
            int fl = (wc << 5) + (r & 3) + ((r >> 2) << 3) + (hi << 2);
            h[r] = fmaxf(acc1[r] + b1s[(ch << 6) + fl], 0.f);
        }
        u32 w[8];
        #pragma unroll
        for (int t = 0; t < 8; t++)
            asm("v_cvt_pk_bf16_f32 %0, %1, %2" : "=v"(w[t]) : "v"(h[2 * t]), "v"(h[2 * t + 1]));
        asm volatile("v_permlane32_swap_b32 %0, %1" : "+v"(w[0]), "+v"(w[2]));
        asm volatile("v_permlane32_swap_b32 %0, %1" : "+v"(w[1]), "+v"(w[3]));
        asm volatile("v_permlane32_swap_b32 %0, %1" : "+v"(w[4]), "+v"(w[6]));
        asm volatile("v_permlane32_swap_b32 %0, %1" : "+v"(w[5]), "+v"(w[7]));
        union { u32x4 u; bf16x8 v; } fr0, fr1, pr0, pr1;
        fr0.u = (u32x4){w[0], w[1], w[2], w[3]};
        fr1.u = (u32x4){w[4], w[5], w[6], w[7]};

        // publish own Ht frags to hs[wr][2wc + 0/1]
        *(u32x4*)(smem + HS_OFF + (wr << 12) + ((wc << 1) << 10) + (lane << 4)) = fr0.u;
        *(u32x4*)(smem + HS_OFF + (wr << 12) + (((wc << 1) + 1) << 10) + (lane << 4)) = fr1.u;

        // B2: hs visible
        asm volatile("s_waitcnt lgkmcnt(0)" ::: "memory");
        __builtin_amdgcn_s_barrier();
        __builtin_amdgcn_sched_barrier(0);

        // write staged chunk ch+1 into buf[cur^1] (overlaps phase 2;
        // safe: all waves past chunk ch-1 since B0)
        {
            char* nbuf = smem + ((cur ^ 1) << 16);
            #pragma unroll
            for (int i = 0; i < 4; i++) {
                int idx = (wid << 2) + i;
                *(u32x4*)(nbuf + (idx << 10) + (lane << 4)) = sg[i];
                *(u32x4*)(nbuf + 32768 + (idx << 10) + (lane << 4)) = sg[4 + i];
            }
        }

        // partner's Ht frags (other wc half)
        pr0.u = *(const u32x4*)(smem + HS_OFF + (wr << 12) + (((wc ^ 1) << 1) << 10) + (lane << 4));
        pr1.u = *(const u32x4*)(smem + HS_OFF + (wr << 12) + ((((wc ^ 1) << 1) + 1) << 10) + (lane << 4));

        // ---- phase 2: acc2[ctl] += W2frag(wc*4+ctl, s2) x Ht(s2), s2=0..3 ----
        const char* w2b = cbuf + 32768 + (wc << 14) + (lane << 4);
        bf16x8 bh0, bh1, bh2, bh3;
        if (wc == 0) { bh0 = fr0.v; bh1 = fr1.v; bh2 = pr0.v; bh3 = pr1.v; }
        else         { bh0 = pr0.v; bh1 = pr1.v; bh2 = fr0.v; bh3 = fr1.v; }

        __builtin_amdgcn_s_setprio(1);
        #define P2_STEP(BH, S2)                                               \
            _Pragma("unroll")                                                 \
            for (int ctl = 0; ctl < 4; ctl++) {                               \
                bf16x8 a = *(const bf16x8*)(w2b + (ctl << 12) + ((S2) << 10));\
                acc2[ctl] = __builtin_amdgcn_mfma_f32_32x32x16_bf16(a, BH, acc2[ctl], 0, 0, 0); \
            }
        P2_STEP(bh0, 0)
        P2_STEP(bh1, 1)
        P2_STEP(bh2, 2)
        P2_STEP(bh3, 3)
        #undef P2_STEP
        __builtin_amdgcn_s_setprio(0);
    }

    // ---- epilogue: each wave owns m-tile wr x c-half wc completely ----
    int m = (wr << 5) + (lane & 31);
    if (m < rows) {
        if (MODE == 0) {
            float* yr = ybuf + ((size_t)(base + m) << 8) + (wc << 7);
            #pragma unroll
            for (int ctl = 0; ctl < 4; ctl++) {
                #pragma unroll
                for (int rq = 0; rq < 4; rq++) {
                    int c = (ctl << 5) + (rq << 3) + (hi << 2);
                    float4 v = {acc2[ctl][4 * rq],     acc2[ctl][4 * rq + 1],
                                acc2[ctl][4 * rq + 2], acc2[ctl][4 * rq + 3]};
                    *(float4*)(yr + c) = v;
                }
            }
        } else {
            float wgt_m = s_w[m];
            float* orow = out + ((size_t)s_tok[m] << 8) + (wc << 7);
            const float* b2w = b2e + (wc << 7);
            #pragma unroll
            for (int ctl = 0; ctl < 4; ctl++) {
                #pragma unroll
                for (int rq = 0; rq < 4; rq++) {
                    int c = (ctl << 5) + (rq << 3) + (hi << 2);
                    #pragma unroll
                    for (int l = 0; l < 4; l++)
                        atomicAdd(&orow[c + l],
                                  wgt_m * (acc2[ctl][4 * rq + l] + b2w[c + l]));
                }
            }
        }
    }
}

__global__ __launch_bounds__(256) void combine_kernel(
    const float* __restrict__ ybuf, const int* __restrict__ tidx,
    const float* __restrict__ tw, const int* __restrict__ pairpos,
    const float* __restrict__ b2, float* __restrict__ out)
{
    int idx = blockIdx.x * 256 + threadIdx.x;
    int n = idx >> 6;
    int q = (idx & 63) << 2;
    int e0 = tidx[2 * n], e1 = tidx[2 * n + 1];
    float w0 = tw[2 * n], w1 = tw[2 * n + 1];
    int p0 = pairpos[2 * n], p1 = pairpos[2 * n + 1];
    float4 y0 = *(const float4*)(ybuf + ((size_t)p0 << 8) + q);
    float4 y1 = *(const float4*)(ybuf + ((size_t)p1 << 8) + q);
    float4 c0 = *(const float4*)(b2 + (e0 << 8) + q);
    float4 c1 = *(const float4*)(b2 + (e1 << 8) + q);
    float4 o;
    o.x = w0 * (y0.x + c0.x) + w1 * (y1.x + c1.x);
    o.y = w0 * (y0.y + c0.y) + w1 * (y1.y + c1.y);
    o.z = w0 * (y0.z + c0.z) + w1 * (y1.z + c1.z);
    o.w = w0 * (y0.w + c0.w) + w1 * (y1.w + c1.w);
    *(float4*)(out + ((size_t)n << 8) + q) = o;
}

extern "C" void kernel_launch(void* const* d_in, const int* in_sizes, int n_in,
                              void* d_out, int out_size, void* d_ws, size_t ws_size,
                              hipStream_t stream)
{
    const float* x   = (const float*)d_in[0];
    const float* gW  = (const float*)d_in[1];
    const float* gb  = (const float*)d_in[2];
    const float* W1  = (const float*)d_in[3];
    const float* b1  = (const float*)d_in[4];
    const float* W2  = (const float*)d_in[5];
    const float* b2  = (const float*)d_in[6];
    float* out = (float*)d_out;

    char* ws = (char*)d_ws;
    int*   topk_idx = (int*)(ws + 0);
    float* topk_w   = (float*)(ws + 262144);
    int*   tok      = (int*)(ws + 524288);
    float* wgt      = (float*)(ws + 786432);
    int*   pairpos  = (int*)(ws + 1048576);
    int*   counts   = (int*)(ws + 1310720);
    int*   fill     = (int*)(ws + 1310784);
    int*   offs     = (int*)(ws + 1310848);
    int*   tp       = (int*)(ws + 1310916);

    const size_t XB_OFF  = 2097152;
    const size_t W1T_OFF = 18874368;
    const size_t W2T_OFF = 27262976;
    const size_t Y_OFF   = 35651584;
    const size_t WS_FULL = Y_OFF + (size_t)2 * N_TOK * C_DIM * 4;

    u16* xb  = (u16*)(ws + XB_OFF);
    u16* w1t = (u16*)(ws + W1T_OFF);
    u16* w2t = (u16*)(ws + W2T_OFF);
    float* ybuf = (float*)(ws + Y_OFF);

    int mode = (ws_size >= WS_FULL) ? 0 : 1;

    hipMemsetAsync(d_out, 0, (size_t)(N_TOK * C_DIM + 1) * sizeof(float), stream);
    hipMemsetAsync(counts, 0, 2 * E_NUM * sizeof(int), stream);

    float* ent_out = out + (size_t)N_TOK * C_DIM;

    gate_kernel<<<N_TOK / 64, 256, 0, stream>>>(x, gW, gb, ent_out,
                                                topk_idx, topk_w, counts, xb);
    prefix_kernel<<<1, 64, 0, stream>>>(counts, offs, tp);
    scatter_kernel<<<N_TOK / 256, 256, 0, stream>>>(topk_idx, topk_w, offs,
                                                    fill, tok, wgt, pairpos);
    tcvt_kernel<<<dim3(E_NUM, C_DIM / 64, F_DIM / 64), 256, 0, stream>>>(W1, w1t, C_DIM, F_DIM);
    tcvt_kernel<<<dim3(E_NUM, F_DIM / 64, C_DIM / 64), 256, 0, stream>>>(W2, w2t, F_DIM, C_DIM);

    if (mode == 0) {
        ffn_mfma<0><<<544, 512, 0, stream>>>(xb, w1t, w2t, b1, b2, tok, wgt,
                                             offs, tp, ybuf, out);
        combine_kernel<<<N_TOK * 64 / 256, 256, 0, stream>>>(ybuf, topk_idx,
                                                             topk_w, pairpos, b2, out);
    } else {
        ffn_mfma<1><<<544, 512, 0, stream>>>(xb, w1t, w2t, b1, b2, tok, wgt,
                                             offs, tp, ybuf, out);
    }
}

// Round 8
// 212.197 us; speedup vs baseline: 1.2808x; 1.0473x over previous
//
#include <hip/hip_runtime.h>
#include <hip/hip_bf16.h>
#include <math.h>

#define N_TOK 32768
#define C_DIM 256
#define F_DIM 1024
#define E_NUM 16
#define TILE_R 128
#define NCH 16
#define NBLK 544   // 8 XCD groups x 68

typedef unsigned short u16;
typedef unsigned int u32;
typedef __attribute__((ext_vector_type(4))) u16 u16x4;
typedef __attribute__((ext_vector_type(8))) u16 u16x8;
typedef __attribute__((ext_vector_type(8))) short bf16x8;
typedef __attribute__((ext_vector_type(4))) u32 u32x4;
typedef __attribute__((ext_vector_type(16))) float f32x16;

#define AS1 __attribute__((address_space(1)))
#define AS3 __attribute__((address_space(3)))

// async global->LDS (prologue only): LDS dest = wave-uniform base + lane*16
__device__ __forceinline__ void gload16(const void* g, void* lds) {
    __builtin_amdgcn_global_load_lds((const AS1 u32*)(uintptr_t)g,
                                     (AS3 u32*)(u32)(uintptr_t)lds, 16, 0, 0);
}

__device__ __forceinline__ u16 f2bf(float f) {
    union { float f; u32 u; } v; v.f = f;
    u32 r = v.u + 0x7fffu + ((v.u >> 16) & 1u);   // RNE
    return (u16)(r >> 16);
}

__device__ __forceinline__ float bf2f(u16 b) {
    union { u32 u; float f; } v; v.u = ((u32)b) << 16;
    return v.f;
}

// ---------------- workspace layout (bytes) ----------------
// 0        topk_idx int[2N]
// 262144   topk_w   f32[2N]
// 524288   tok      int[2N]
// 786432   wgt      f32[2N]
// 1048576  pairpos  int[2N]
// 1310720  counts[16] fill[16] offs[17] tp[17]
// 2097152  xb   bf16[N][C]
// 18874368 w1t  bf16[E][F][C]
// 27262976 w2t  bf16[E][C][F]
// 35651584 ybuf bf16[2N][C]  (MODE 0 only, 33.5 MB)

// ---- gate: 64 tokens/block, 4 lanes/token, fused x->bf16 conversion ----
__global__ __launch_bounds__(256) void gate_kernel(
    const float* __restrict__ x, const float* __restrict__ gW,
    const float* __restrict__ gb, float* __restrict__ ent_out,
    int* __restrict__ tidx, float* __restrict__ tw, int* __restrict__ counts,
    u16* __restrict__ xb)
{
    __shared__ float gws[E_NUM * C_DIM];
    __shared__ float gbs[E_NUM];
    __shared__ float went[4];
    __shared__ int lc[E_NUM];
    int tid = threadIdx.x;

    for (int i = tid; i < E_NUM * C_DIM / 4; i += 256)
        ((float4*)gws)[i] = ((const float4*)gW)[i];
    if (tid < E_NUM) { gbs[tid] = gb[tid]; lc[tid] = 0; }
    __syncthreads();

    int tok = tid >> 2, q = tid & 3;
    int n = blockIdx.x * 64 + tok;
    const float* xr = x + (size_t)n * C_DIM;

    float4 xv[16];
    #pragma unroll
    for (int j = 0; j < 16; j++)
        xv[j] = *(const float4*)(xr + j * 16 + q * 4);

    #pragma unroll
    for (int j = 0; j < 16; j++) {
        u16x4 o;
        o[0] = f2bf(xv[j].x); o[1] = f2bf(xv[j].y);
        o[2] = f2bf(xv[j].z); o[3] = f2bf(xv[j].w);
        *(u16x4*)(xb + (size_t)n * C_DIM + j * 16 + q * 4) = o;
    }

    float lg[E_NUM];
    #pragma unroll
    for (int e = 0; e < E_NUM; e++) lg[e] = 0.f;
    #pragma unroll
    for (int j = 0; j < 16; j++) {
        #pragma unroll
        for (int e = 0; e < E_NUM; e++) {
            float4 g = *(const float4*)(gws + e * C_DIM + j * 16 + q * 4);
            lg[e] += xv[j].x * g.x + xv[j].y * g.y + xv[j].z * g.z + xv[j].w * g.w;
        }
    }
    #pragma unroll
    for (int e = 0; e < E_NUM; e++) {
        lg[e] += __shfl_xor(lg[e], 1);
        lg[e] += __shfl_xor(lg[e], 2);
        lg[e] += gbs[e];
    }

    float m = lg[0];
    #pragma unroll
    for (int e = 1; e < E_NUM; e++) m = fmaxf(m, lg[e]);
    float s = 0.f, ex[E_NUM];
    #pragma unroll
    for (int e = 0; e < E_NUM; e++) { ex[e] = __expf(lg[e] - m); s += ex[e]; }
    float inv = 1.f / s;
    float ent = 0.f;
    #pragma unroll
    for (int e = 0; e < E_NUM; e++) {
        float p = ex[e] * inv;
        ent -= p * logf(p + 1e-8f);
    }

    float v0 = -1e30f, v1 = -1e30f;
    int i0 = 0, i1 = 0;
    #pragma unroll
    for (int e = 0; e < E_NUM; e++) {
        float l = lg[e];
        if (l > v0) { v1 = v0; i1 = i0; v0 = l; i0 = e; }
        else if (l > v1) { v1 = l; i1 = e; }
    }
    if (q == 0) {
        float w1e = __expf(v1 - v0);
        float z = 1.f + w1e;
        tidx[2 * n] = i0; tidx[2 * n + 1] = i1;
        tw[2 * n] = 1.f / z; tw[2 * n + 1] = w1e / z;
        atomicAdd(&lc[i0], 1);
        atomicAdd(&lc[i1], 1);
    }

    float v = ent;   // 4x duplicated per token -> scale 1/(4N)
    for (int off = 32; off > 0; off >>= 1) v += __shfl_down(v, off);
    int wid = tid >> 6, lane = tid & 63;
    if (lane == 0) went[wid] = v;
    __syncthreads();
    if (tid == 0)
        atomicAdd(ent_out, (went[0] + went[1] + went[2] + went[3]) * (1.0f / (4.0f * N_TOK)));
    if (tid < E_NUM && lc[tid]) atomicAdd(&counts[tid], lc[tid]);
}

__global__ void prefix_kernel(const int* __restrict__ counts,
                              int* __restrict__ offs, int* __restrict__ tp)
{
    if (threadIdx.x == 0 && blockIdx.x == 0) {
        int o = 0, t = 0;
        offs[0] = 0; tp[0] = 0;
        for (int e = 0; e < E_NUM; e++) {
            o += counts[e];
            t += (counts[e] + TILE_R - 1) / TILE_R;
            offs[e + 1] = o;
            tp[e + 1] = t;
        }
    }
}

__global__ __launch_bounds__(256) void scatter_kernel(
    const int* __restrict__ tidx, const float* __restrict__ tw,
    const int* __restrict__ offs, int* __restrict__ fill,
    int* __restrict__ tok, float* __restrict__ wgt, int* __restrict__ pairpos)
{
    __shared__ int lc[E_NUM], lbase[E_NUM];
    int tid = threadIdx.x;
    if (tid < E_NUM) lc[tid] = 0;
    __syncthreads();
    int n = blockIdx.x * 256 + tid;
    int e0 = tidx[2 * n], e1 = tidx[2 * n + 1];
    int r0 = atomicAdd(&lc[e0], 1);
    int r1 = atomicAdd(&lc[e1], 1);
    __syncthreads();
    if (tid < E_NUM) lbase[tid] = offs[tid] + atomicAdd(&fill[tid], lc[tid]);
    __syncthreads();
    int p0 = lbase[e0] + r0, p1 = lbase[e1] + r1;
    tok[p0] = n; wgt[p0] = tw[2 * n];     pairpos[2 * n] = p0;
    tok[p1] = n; wgt[p1] = tw[2 * n + 1]; pairpos[2 * n + 1] = p1;
}

// per-expert transpose+convert: src f32 [R][Cc] -> dst bf16 [Cc][R]
__global__ __launch_bounds__(256) void tcvt_kernel(
    const float* __restrict__ src, u16* __restrict__ dst, int R, int Cc)
{
    __shared__ float t[64][65];
    int e = blockIdx.x;
    int r0 = blockIdx.y << 6, c0 = blockIdx.z << 6;
    const float* s = src + (size_t)e * R * Cc;
    u16* d = dst + (size_t)e * R * Cc;
    int tid = threadIdx.x;
    int rr = tid >> 4, cc = (tid & 15) << 2;
    #pragma unroll
    for (int it = 0; it < 4; it++) {
        float4 v = *(const float4*)(s + (size_t)(r0 + rr + it * 16) * Cc + c0 + cc);
        t[rr + it * 16][cc] = v.x; t[rr + it * 16][cc + 1] = v.y;
        t[rr + it * 16][cc + 2] = v.z; t[rr + it * 16][cc + 3] = v.w;
    }
    __syncthreads();
    int cr = tid >> 3, rq = (tid & 7) << 3;
    #pragma unroll
    for (int it = 0; it < 2; it++) {
        int c = cr + it * 32;
        u16x8 o;
        #pragma unroll
        for (int j = 0; j < 8; j++) o[j] = f2bf(t[rq + j][c]);
        *(u16x8*)(d + (size_t)(c0 + c) * R + r0 + rq) = o;
    }
}

// ---- FFN: 128-token tile, 8 waves, 32x32x16 MFMA, reg-staged pipeline ----
// Expert-locality XCD swizzle: logical block L = (idx%8)*68 + idx/8, so each
// XCD serves a contiguous ~2-expert range (2 MB weights, L2-resident).
#define HS_OFF  131072
#define B1S_OFF 147456

template <int MODE>
__global__ __launch_bounds__(512, 2) void ffn_mfma(
    const u16* __restrict__ xb, const u16* __restrict__ w1t,
    const u16* __restrict__ w2t, const float* __restrict__ b1,
    const float* __restrict__ b2, const int* __restrict__ tok,
    const float* __restrict__ wgt, const int* __restrict__ offs,
    const int* __restrict__ tp, u16* __restrict__ ybuf,
    float* __restrict__ out)
{
    __shared__ __align__(1024) char smem[152576];
    int* s_tok = (int*)(smem + 151552);
    float* s_w = (float*)(smem + 152064);
    float* b1s = (float*)(smem + B1S_OFF);

    int idx = blockIdx.x;
    int b = (idx & 7) * (NBLK / 8) + (idx >> 3);   // XCD-locality remap
    if (b >= tp[E_NUM]) return;
    int e = 0;
    while (b >= tp[e + 1]) e++;
    int base = offs[e] + ((b - tp[e]) << 7);
    int rows = offs[e + 1] - base; if (rows > TILE_R) rows = TILE_R;

    int tid = threadIdx.x;
    int lane = tid & 63, wid = tid >> 6;
    int hi = lane >> 5;
    int wr = wid >> 1, wc = wid & 1;

    const u16* w1e = w1t + (size_t)e * (F_DIM * C_DIM);   // [F][C]
    const u16* w2e = w2t + (size_t)e * (C_DIM * F_DIM);   // [C][F]
    const float* b1e = b1 + e * F_DIM;
    const float* b2e = b2 + e * C_DIM;

    if (tid < TILE_R) {
        int src = (tid < rows) ? base + tid : base;
        s_tok[tid] = tok[src];
        s_w[tid] = (tid < rows) ? wgt[src] : 0.f;
    }
    if (tid < 256) ((float4*)b1s)[tid] = ((const float4*)b1e)[tid];
    __syncthreads();

    // ---- prologue: stage x tile through LDS (stg region), hoist to regs ----
    #pragma unroll
    for (int i = 0; i < 8; i++) {
        int idx2 = (wid << 3) + i;
        int row = ((idx2 >> 4) << 5) + (lane & 31);
        gload16(xb + ((size_t)s_tok[row] << 8) + ((idx2 & 15) << 4) + (hi << 3),
                smem + (idx2 << 10));
    }
    __syncthreads();   // one-time vmcnt(0) drain, fine

    bf16x8 xr[16];     // this wave's m-tile (wr), 16 k-slices: 64 VGPR
    #pragma unroll
    for (int ks = 0; ks < 16; ks++)
        xr[ks] = *(const bf16x8*)(smem + (wr << 14) + (ks << 10) + (lane << 4));
    __syncthreads();   // xr in regs; stg region free

    // ---- stage chunk 0 via regs into buf 0 ----
    u32x4 sg[8];
    #pragma unroll
    for (int i = 0; i < 4; i++) {
        int idx2 = (wid << 2) + i;
        int f = ((idx2 >> 4) << 5) + (lane & 31);
        sg[i] = *(const u32x4*)(w1e + ((size_t)f << 8) + ((idx2 & 15) << 4) + (hi << 3));
        int c = ((idx2 >> 2) << 5) + (lane & 31);
        sg[4 + i] = *(const u32x4*)(w2e + ((size_t)c << 10) + ((idx2 & 3) << 4) + (hi << 3));
    }
    #pragma unroll
    for (int i = 0; i < 4; i++) {
        int idx2 = (wid << 2) + i;
        *(u32x4*)(smem + (idx2 << 10) + (lane << 4)) = sg[i];
        *(u32x4*)(smem + 32768 + (idx2 << 10) + (lane << 4)) = sg[4 + i];
    }

    f32x16 acc2[4];
    #pragma unroll
    for (int ct = 0; ct < 4; ct++) acc2[ct] = (f32x16)(0.0f);

    for (int ch = 0; ch < NCH; ch++) {
        int cur = ch & 1;
        const char* cbuf = smem + (cur << 16);

        // B0: buf[cur] writes visible (writers drained own lgkm first)
        asm volatile("s_waitcnt lgkmcnt(0)" ::: "memory");
        __builtin_amdgcn_s_barrier();
        __builtin_amdgcn_sched_barrier(0);

        // issue chunk ch+1 loads -> regs (waited only at the ds_write below)
        {
            int chn = ch + 1; if (chn == NCH) chn = NCH - 1;
            #pragma unroll
            for (int i = 0; i < 4; i++) {
                int idx2 = (wid << 2) + i;
                int f = (chn << 6) + ((idx2 >> 4) << 5) + (lane & 31);
                sg[i] = *(const u32x4*)(w1e + ((size_t)f << 8) + ((idx2 & 15) << 4) + (hi << 3));
                int c = ((idx2 >> 2) << 5) + (lane & 31);
                sg[4 + i] = *(const u32x4*)(w2e + ((size_t)c << 10) + (chn << 6) + ((idx2 & 3) << 4) + (hi << 3));
            }
        }

        // ---- phase 1: Ht = W1 x X^T -> D[f][m], split into 2 chains ----
        const char* w1b = cbuf + (wc << 14) + (lane << 4);
        f32x16 acc1a = (f32x16)(0.0f), acc1b = (f32x16)(0.0f);
        __builtin_amdgcn_s_setprio(1);
        #pragma unroll
        for (int ks = 0; ks < 8; ks++) {
            bf16x8 a0 = *(const bf16x8*)(w1b + ((2 * ks) << 10));
            bf16x8 a1 = *(const bf16x8*)(w1b + ((2 * ks + 1) << 10));
            acc1a = __builtin_amdgcn_mfma_f32_32x32x16_bf16(a0, xr[2 * ks], acc1a, 0, 0, 0);
            acc1b = __builtin_amdgcn_mfma_f32_32x32x16_bf16(a1, xr[2 * ks + 1], acc1b, 0, 0, 0);
        }
        __builtin_amdgcn_s_setprio(0);

        // bias + relu -> bf16 B-frags (k-slices 2wc, 2wc+1) in regs
        float h[16];
        #pragma unroll
        for (int r = 0; r < 16; r++) {
            int fl = (wc << 5) + (r & 3) + ((r >> 2) << 3) + (hi << 2);
            h[r] = fmaxf(acc1a[r] + acc1b[r] + b1s[(ch << 6) + fl], 0.f);
        }
        u32 w[8];
        #pragma unroll
        for (int t = 0; t < 8; t++)
            asm("v_cvt_pk_bf16_f32 %0, %1, %2" : "=v"(w[t]) : "v"(h[2 * t]), "v"(h[2 * t + 1]));
        asm volatile("v_permlane32_swap_b32 %0, %1" : "+v"(w[0]), "+v"(w[2]));
        asm volatile("v_permlane32_swap_b32 %0, %1" : "+v"(w[1]), "+v"(w[3]));
        asm volatile("v_permlane32_swap_b32 %0, %1" : "+v"(w[4]), "+v"(w[6]));
        asm volatile("v_permlane32_swap_b32 %0, %1" : "+v"(w[5]), "+v"(w[7]));
        union { u32x4 u; bf16x8 v; } fr0, fr1, pr0, pr1;
        fr0.u = (u32x4){w[0], w[1], w[2], w[3]};
        fr1.u = (u32x4){w[4], w[5], w[6], w[7]};

        // publish own Ht frags to hs[wr][2wc + 0/1]
        *(u32x4*)(smem + HS_OFF + (wr << 12) + ((wc << 1) << 10) + (lane << 4)) = fr0.u;
        *(u32x4*)(smem + HS_OFF + (wr << 12) + (((wc << 1) + 1) << 10) + (lane << 4)) = fr1.u;

        // B2: hs visible
        asm volatile("s_waitcnt lgkmcnt(0)" ::: "memory");
        __builtin_amdgcn_s_barrier();
        __builtin_amdgcn_sched_barrier(0);

        // write staged chunk ch+1 into buf[cur^1] (overlaps phase 2)
        {
            char* nbuf = smem + ((cur ^ 1) << 16);
            #pragma unroll
            for (int i = 0; i < 4; i++) {
                int idx2 = (wid << 2) + i;
                *(u32x4*)(nbuf + (idx2 << 10) + (lane << 4)) = sg[i];
                *(u32x4*)(nbuf + 32768 + (idx2 << 10) + (lane << 4)) = sg[4 + i];
            }
        }

        // partner's Ht frags (other wc half)
        pr0.u = *(const u32x4*)(smem + HS_OFF + (wr << 12) + (((wc ^ 1) << 1) << 10) + (lane << 4));
        pr1.u = *(const u32x4*)(smem + HS_OFF + (wr << 12) + ((((wc ^ 1) << 1) + 1) << 10) + (lane << 4));

        // ---- phase 2: acc2[ctl] += W2frag(wc*4+ctl, s2) x Ht(s2) ----
        const char* w2b = cbuf + 32768 + (wc << 14) + (lane << 4);
        bf16x8 bh0, bh1, bh2, bh3;
        if (wc == 0) { bh0 = fr0.v; bh1 = fr1.v; bh2 = pr0.v; bh3 = pr1.v; }
        else         { bh0 = pr0.v; bh1 = pr1.v; bh2 = fr0.v; bh3 = fr1.v; }

        __builtin_amdgcn_s_setprio(1);
        #define P2_STEP(BH, S2)                                               \
            _Pragma("unroll")                                                 \
            for (int ctl = 0; ctl < 4; ctl++) {                               \
                bf16x8 a = *(const bf16x8*)(w2b + (ctl << 12) + ((S2) << 10));\
                acc2[ctl] = __builtin_amdgcn_mfma_f32_32x32x16_bf16(a, BH, acc2[ctl], 0, 0, 0); \
            }
        P2_STEP(bh0, 0)
        P2_STEP(bh1, 1)
        P2_STEP(bh2, 2)
        P2_STEP(bh3, 3)
        #undef P2_STEP
        __builtin_amdgcn_s_setprio(0);
    }

    // ---- epilogue: each wave owns m-tile wr x c-half wc completely ----
    int m = (wr << 5) + (lane & 31);
    if (m < rows) {
        if (MODE == 0) {
            u16* yr = ybuf + ((size_t)(base + m) << 8) + (wc << 7);
            #pragma unroll
            for (int ctl = 0; ctl < 4; ctl++) {
                #pragma unroll
                for (int rq = 0; rq < 4; rq++) {
                    int c = (ctl << 5) + (rq << 3) + (hi << 2);
                    u16x4 o;
                    o[0] = f2bf(acc2[ctl][4 * rq]);
                    o[1] = f2bf(acc2[ctl][4 * rq + 1]);
                    o[2] = f2bf(acc2[ctl][4 * rq + 2]);
                    o[3] = f2bf(acc2[ctl][4 * rq + 3]);
                    *(u16x4*)(yr + c) = o;
                }
            }
        } else {
            float wgt_m = s_w[m];
            float* orow = out + ((size_t)s_tok[m] << 8) + (wc << 7);
            const float* b2w = b2e + (wc << 7);
            #pragma unroll
            for (int ctl = 0; ctl < 4; ctl++) {
                #pragma unroll
                for (int rq = 0; rq < 4; rq++) {
                    int c = (ctl << 5) + (rq << 3) + (hi << 2);
                    #pragma unroll
                    for (int l = 0; l < 4; l++)
                        atomicAdd(&orow[c + l],
                                  wgt_m * (acc2[ctl][4 * rq + l] + b2w[c + l]));
                }
            }
        }
    }
}

__global__ __launch_bounds__(256) void combine_kernel(
    const u16* __restrict__ ybuf, const int* __restrict__ tidx,
    const float* __restrict__ tw, const int* __restrict__ pairpos,
    const float* __restrict__ b2, float* __restrict__ out)
{
    int idx = blockIdx.x * 256 + threadIdx.x;
    int n = idx >> 6;
    int q = (idx & 63) << 2;
    int e0 = tidx[2 * n], e1 = tidx[2 * n + 1];
    float w0 = tw[2 * n], w1 = tw[2 * n + 1];
    int p0 = pairpos[2 * n], p1 = pairpos[2 * n + 1];
    u16x4 y0 = *(const u16x4*)(ybuf + ((size_t)p0 << 8) + q);
    u16x4 y1 = *(const u16x4*)(ybuf + ((size_t)p1 << 8) + q);
    float4 c0 = *(const float4*)(b2 + (e0 << 8) + q);
    float4 c1 = *(const float4*)(b2 + (e1 << 8) + q);
    float4 o;
    o.x = w0 * (bf2f(y0[0]) + c0.x) + w1 * (bf2f(y1[0]) + c1.x);
    o.y = w0 * (bf2f(y0[1]) + c0.y) + w1 * (bf2f(y1[1]) + c1.y);
    o.z = w0 * (bf2f(y0[2]) + c0.z) + w1 * (bf2f(y1[2]) + c1.z);
    o.w = w0 * (bf2f(y0[3]) + c0.w) + w1 * (bf2f(y1[3]) + c1.w);
    *(float4*)(out + ((size_t)n << 8) + q) = o;
}

extern "C" void kernel_launch(void* const* d_in, const int* in_sizes, int n_in,
                              void* d_out, int out_size, void* d_ws, size_t ws_size,
                              hipStream_t stream)
{
    const float* x   = (const float*)d_in[0];
    const float* gW  = (const float*)d_in[1];
    const float* gb  = (const float*)d_in[2];
    const float* W1  = (const float*)d_in[3];
    const float* b1  = (const float*)d_in[4];
    const float* W2  = (const float*)d_in[5];
    const float* b2  = (const float*)d_in[6];
    float* out = (float*)d_out;

    char* ws = (char*)d_ws;
    int*   topk_idx = (int*)(ws + 0);
    float* topk_w   = (float*)(ws + 262144);
    int*   tok      = (int*)(ws + 524288);
    float* wgt      = (float*)(ws + 786432);
    int*   pairpos  = (int*)(ws + 1048576);
    int*   counts   = (int*)(ws + 1310720);
    int*   fill     = (int*)(ws + 1310784);
    int*   offs     = (int*)(ws + 1310848);
    int*   tp       = (int*)(ws + 1310916);

    const size_t XB_OFF  = 2097152;
    const size_t W1T_OFF = 18874368;
    const size_t W2T_OFF = 27262976;
    const size_t Y_OFF   = 35651584;
    const size_t WS_FULL = Y_OFF + (size_t)2 * N_TOK * C_DIM * 2;  // bf16 ybuf

    u16* xb  = (u16*)(ws + XB_OFF);
    u16* w1t = (u16*)(ws + W1T_OFF);
    u16* w2t = (u16*)(ws + W2T_OFF);
    u16* ybuf = (u16*)(ws + Y_OFF);

    int mode = (ws_size >= WS_FULL) ? 0 : 1;

    float* ent_out = out + (size_t)N_TOK * C_DIM;

    if (mode == 0) {
        // combine fully overwrites out; only entropy accumulator needs zeroing
        hipMemsetAsync(ent_out, 0, sizeof(float), stream);
    } else {
        hipMemsetAsync(d_out, 0, (size_t)(N_TOK * C_DIM + 1) * sizeof(float), stream);
    }
    hipMemsetAsync(counts, 0, 2 * E_NUM * sizeof(int), stream);

    gate_kernel<<<N_TOK / 64, 256, 0, stream>>>(x, gW, gb, ent_out,
                                                topk_idx, topk_w, counts, xb);
    prefix_kernel<<<1, 64, 0, stream>>>(counts, offs, tp);
    scatter_kernel<<<N_TOK / 256, 256, 0, stream>>>(topk_idx, topk_w, offs,
                                                    fill, tok, wgt, pairpos);
    tcvt_kernel<<<dim3(E_NUM, C_DIM / 64, F_DIM / 64), 256, 0, stream>>>(W1, w1t, C_DIM, F_DIM);
    tcvt_kernel<<<dim3(E_NUM, F_DIM / 64, C_DIM / 64), 256, 0, stream>>>(W2, w2t, F_DIM, C_DIM);

    if (mode == 0) {
        ffn_mfma<0><<<NBLK, 512, 0, stream>>>(xb, w1t, w2t, b1, b2, tok, wgt,
                                              offs, tp, ybuf, out);
        combine_kernel<<<N_TOK * 64 / 256, 256, 0, stream>>>(ybuf, topk_idx,
                                                             topk_w, pairpos, b2, out);
    } else {
        ffn_mfma<1><<<NBLK, 512, 0, stream>>>(xb, w1t, w2t, b1, b2, tok, wgt,
                                              offs, tp, ybuf, out);
    }
}